// Round 1
// baseline (2583.897 us; speedup 1.0000x reference)
//
#include <hip/hip_runtime.h>

#define N_NODES 50000
#define N_EDGES 600000
#define N_GRAPHS 128
#define D 128
#define DE 64
#define N_LAYERS 4
#define BN_EPS 1e-5f
#define ECHUNK 8

// ---------------- copy: agg <- x ----------------
__global__ void copy_f4(const float4* __restrict__ src, float4* __restrict__ dst, int n4) {
    int i = blockIdx.x * blockDim.x + threadIdx.x;
    int stride = gridDim.x * blockDim.x;
    for (; i < n4; i += stride) dst[i] = src[i];
}

// ---------------- fused edge transform + gather + relu + scatter-add ----------------
// agg[dst] += relu(x[src] + edge_attr @ We + be)
// 128 threads/block (2 waves); thread t owns output column t; We column in 64 VGPRs.
__global__ __launch_bounds__(128) void edge_kernel(
    const float* __restrict__ xin,   // [N, D]
    const int*   __restrict__ ei,    // [2, E]
    const float* __restrict__ ea,    // [E, 64]
    const float* __restrict__ We,    // [64, D]  (layer slice)
    const float* __restrict__ be,    // [D]
    float* __restrict__ agg)         // [N, D]
{
    __shared__ float eas[ECHUNK * DE];   // 2 KiB
    const int t = threadIdx.x;
    float w[DE];
#pragma unroll
    for (int k = 0; k < DE; k++) w[k] = We[k * D + t];
    const float bias = be[t];

    const int nch = N_EDGES / ECHUNK;   // 75000, exact
    for (int ch = blockIdx.x; ch < nch; ch += gridDim.x) {
        const int e0 = ch * ECHUNK;
        // stage ECHUNK*64 = 512 contiguous floats as 128 float4s
        ((float4*)eas)[t] = ((const float4*)(ea + (size_t)e0 * DE))[t];
        __syncthreads();
#pragma unroll
        for (int j = 0; j < ECHUNK; j++) {
            const int e = e0 + j;
            const int s = ei[e];
            const int d = ei[N_EDGES + e];
            float acc = bias;
            const float4* v4 = (const float4*)(eas + j * DE);  // uniform addr -> ds_read_b128 broadcast
#pragma unroll
            for (int k4 = 0; k4 < DE / 4; k4++) {
                float4 v = v4[k4];
                acc += v.x * w[4 * k4 + 0];
                acc += v.y * w[4 * k4 + 1];
                acc += v.z * w[4 * k4 + 2];
                acc += v.w * w[4 * k4 + 3];
            }
            float msg = xin[(size_t)s * D + t] + acc;
            msg = msg > 0.f ? msg : 0.f;
            unsafeAtomicAdd(&agg[(size_t)d * D + t], msg);
        }
        __syncthreads();
    }
}

// ---------------- node GEMM: out = act(BN?(in @ W + bias)) ----------------
// 256 threads; W (128x128 fp32, 64 KiB) in LDS; thread computes 4 cols of 1 row per
// 8-row group; h row values read via wave-broadcast global loads (L1-served).
__global__ __launch_bounds__(256) void node_gemm(
    const float* __restrict__ in,     // [N, D]
    const float* __restrict__ W,      // [D, D]
    const float* __restrict__ bias,   // [D]
    const float* __restrict__ gamma, const float* __restrict__ beta,
    const float* __restrict__ rm,    const float* __restrict__ rv,
    int do_relu,
    float* __restrict__ out)          // [N, D]
{
    __shared__ float Ws[D * D];       // 65536 B
    const int tid = threadIdx.x;
    {
        const float4* Wsrc = (const float4*)W;
        float4* Wd = (float4*)Ws;
#pragma unroll
        for (int i = 0; i < (D * D / 4) / 256; i++)   // 16 iters
            Wd[tid + i * 256] = Wsrc[tid + i * 256];
    }
    __syncthreads();

    const int c0 = (tid & 31) * 4;
    const int r  = tid >> 5;          // 0..7

    float b0[4], sc[4], sh[4];
#pragma unroll
    for (int j = 0; j < 4; j++) {
        int c = c0 + j;
        b0[j] = bias[c];
        if (gamma != nullptr) {
            float s = gamma[c] * rsqrtf(rv[c] + BN_EPS);
            sc[j] = s; sh[j] = beta[c] - rm[c] * s;
        } else { sc[j] = 1.f; sh[j] = 0.f; }
    }

    const int ngroups = N_NODES / 8;   // 6250, exact
    for (int g = blockIdx.x; g < ngroups; g += gridDim.x) {
        const int row = g * 8 + r;
        const float* hrow = in + (size_t)row * D;
        float ax = 0.f, ay = 0.f, az = 0.f, aw = 0.f;
#pragma unroll
        for (int k0 = 0; k0 < D; k0 += 16) {
            float4 h4[4];
#pragma unroll
            for (int u = 0; u < 4; u++) h4[u] = *(const float4*)(hrow + k0 + u * 4);
#pragma unroll
            for (int u = 0; u < 4; u++) {
                const float hv[4] = {h4[u].x, h4[u].y, h4[u].z, h4[u].w};
#pragma unroll
                for (int q = 0; q < 4; q++) {
                    const int k = k0 + u * 4 + q;
                    float4 wv = *(const float4*)(Ws + k * D + c0);
                    ax += hv[q] * wv.x;
                    ay += hv[q] * wv.y;
                    az += hv[q] * wv.z;
                    aw += hv[q] * wv.w;
                }
            }
        }
        float o[4] = {ax, ay, az, aw};
#pragma unroll
        for (int j = 0; j < 4; j++) {
            float v = (o[j] + b0[j]) * sc[j] + sh[j];
            if (do_relu) v = v > 0.f ? v : 0.f;
            o[j] = v;
        }
        *(float4*)(out + (size_t)row * D + c0) = make_float4(o[0], o[1], o[2], o[3]);
    }
}

// ---------------- global mean pool (batch is sorted) ----------------
__global__ __launch_bounds__(128) void pool_kernel(
    const float* __restrict__ xin, const int* __restrict__ batch,
    float* __restrict__ out)
{
    const int g = blockIdx.x;
    const int t = threadIdx.x;
    int lo = 0, hi = N_NODES;
    while (lo < hi) { int m = (lo + hi) >> 1; if (batch[m] < g) lo = m + 1; else hi = m; }
    int lo2 = lo, hi2 = N_NODES;
    while (lo2 < hi2) { int m = (lo2 + hi2) >> 1; if (batch[m] < g + 1) lo2 = m + 1; else hi2 = m; }
    float sum = 0.f;
    for (int rr = lo; rr < lo2; rr++) sum += xin[(size_t)rr * D + t];
    const int cnt = lo2 - lo;
    out[g * D + t] = sum / (float)(cnt > 0 ? cnt : 1);
}

extern "C" void kernel_launch(void* const* d_in, const int* in_sizes, int n_in,
                              void* d_out, int out_size, void* d_ws, size_t ws_size,
                              hipStream_t stream) {
    const float* x     = (const float*)d_in[0];
    const int*   ei    = (const int*)  d_in[1];
    const float* ea    = (const float*)d_in[2];
    const int*   batch = (const int*)  d_in[3];
    const float* We    = (const float*)d_in[4];
    const float* be    = (const float*)d_in[5];
    const float* W1    = (const float*)d_in[6];
    const float* b1    = (const float*)d_in[7];
    const float* gamma = (const float*)d_in[8];
    const float* beta  = (const float*)d_in[9];
    const float* rm    = (const float*)d_in[10];
    const float* rv    = (const float*)d_in[11];
    const float* W2    = (const float*)d_in[12];
    const float* b2    = (const float*)d_in[13];
    float* out = (float*)d_out;

    float* bufA = (float*)d_ws;
    float* bufB = bufA + (size_t)N_NODES * D;

    const float* cur = x;
    float* aggb = bufA;
    float* tb   = bufB;
    for (int i = 0; i < N_LAYERS; i++) {
        // agg = cur (the "+x" self term), then edges atomically add messages
        copy_f4<<<1024, 256, 0, stream>>>((const float4*)cur, (float4*)aggb, N_NODES * D / 4);
        edge_kernel<<<4096, 128, 0, stream>>>(cur, ei, ea, We + (size_t)i * DE * D, be + (size_t)i * D, aggb);
        node_gemm<<<2048, 256, 0, stream>>>(aggb, W1 + (size_t)i * D * D, b1 + (size_t)i * D,
                                            gamma + (size_t)i * D, beta + (size_t)i * D,
                                            rm + (size_t)i * D, rv + (size_t)i * D, 1, tb);
        node_gemm<<<2048, 256, 0, stream>>>(tb, W2 + (size_t)i * D * D, b2 + (size_t)i * D,
                                            nullptr, nullptr, nullptr, nullptr,
                                            (i != N_LAYERS - 1) ? 1 : 0, aggb);
        cur = aggb;
        float* tmp = aggb; aggb = tb; tb = tmp;
    }
    pool_kernel<<<N_GRAPHS, D, 0, stream>>>(cur, batch, out);
}

// Round 2
// 1527.292 us; speedup vs baseline: 1.6918x; 1.6918x over previous
//
#include <hip/hip_runtime.h>

#define N_NODES 50000
#define N_EDGES 600000
#define N_GRAPHS 128
#define D 128
#define DE 64
#define N_LAYERS 4
#define BN_EPS 1e-5f
#define ECHUNK 8

#define MLP_ROWS 64
#define LDST 136   // padded LDS row stride in bf16 elements (272 B -> 2-way max conflict)

typedef __attribute__((ext_vector_type(8))) short short8;
typedef __attribute__((ext_vector_type(4))) float floatx4;

__device__ __forceinline__ unsigned short f2bf(float f) {
    union { float f; unsigned u; } v; v.f = f;
    unsigned r = v.u + 0x7FFF + ((v.u >> 16) & 1);  // RNE
    return (unsigned short)(r >> 16);
}

// ---------------- copy: agg <- x ----------------
__global__ void copy_f4(const float4* __restrict__ src, float4* __restrict__ dst, int n4) {
    int i = blockIdx.x * blockDim.x + threadIdx.x;
    int stride = gridDim.x * blockDim.x;
    for (; i < n4; i += stride) dst[i] = src[i];
}

// ---------------- fused edge transform + gather + relu + scatter-add ----------------
__global__ __launch_bounds__(128) void edge_kernel(
    const float* __restrict__ xin, const int* __restrict__ ei,
    const float* __restrict__ ea,  const float* __restrict__ We,
    const float* __restrict__ be,  float* __restrict__ agg)
{
    __shared__ float eas[ECHUNK * DE];
    const int t = threadIdx.x;
    float w[DE];
#pragma unroll
    for (int k = 0; k < DE; k++) w[k] = We[k * D + t];
    const float bias = be[t];

    const int nch = N_EDGES / ECHUNK;
    for (int ch = blockIdx.x; ch < nch; ch += gridDim.x) {
        const int e0 = ch * ECHUNK;
        ((float4*)eas)[t] = ((const float4*)(ea + (size_t)e0 * DE))[t];
        __syncthreads();
#pragma unroll
        for (int j = 0; j < ECHUNK; j++) {
            const int e = e0 + j;
            const int s = ei[e];
            const int d = ei[N_EDGES + e];
            float acc = bias;
            const float4* v4 = (const float4*)(eas + j * DE);
#pragma unroll
            for (int k4 = 0; k4 < DE / 4; k4++) {
                float4 v = v4[k4];
                acc += v.x * w[4 * k4 + 0];
                acc += v.y * w[4 * k4 + 1];
                acc += v.z * w[4 * k4 + 2];
                acc += v.w * w[4 * k4 + 3];
            }
            float msg = xin[(size_t)s * D + t] + acc;
            msg = msg > 0.f ? msg : 0.f;
            unsafeAtomicAdd(&agg[(size_t)d * D + t], msg);
        }
        __syncthreads();
    }
}

// ---------------- fused node MLP: out = act2(BNrelu(in@W1+b1) @ W2 + b2), in-place OK ----
// 256 threads (4 waves). Persistent blocks: W1^T/W2^T bf16 in LDS once, then tiles of 64 rows.
// Wave w owns rows 16w..16w+15 of the tile; MFMA 16x16x32 bf16, fp32 accumulate.
__global__ __launch_bounds__(256) void mlp_kernel(
    float* __restrict__ io,          // [N, D] read and written in-place
    const float* __restrict__ W1, const float* __restrict__ b1,
    const float* __restrict__ gamma, const float* __restrict__ beta,
    const float* __restrict__ rm,    const float* __restrict__ rv,
    const float* __restrict__ W2, const float* __restrict__ b2,
    int relu2)
{
    __shared__ __align__(16) unsigned short Wt1[D * LDST];   // W1^T bf16: [n][k]
    __shared__ __align__(16) unsigned short Wt2[D * LDST];
    __shared__ __align__(16) unsigned short At[MLP_ROWS * LDST]; // A tile, then T1 tile
    __shared__ float alpha_s[D], betac_s[D], b2_s[D];

    const int tid = threadIdx.x;

    // Stage transposed bf16 weights: W[k][n] (global, row-major) -> Wt[n][k]
    for (int i = tid; i < D * (D / 4); i += 256) {
        const int k = i >> 5;
        const int n0 = (i & 31) * 4;
        float4 w = *(const float4*)(W1 + (size_t)k * D + n0);
        Wt1[(n0 + 0) * LDST + k] = f2bf(w.x);
        Wt1[(n0 + 1) * LDST + k] = f2bf(w.y);
        Wt1[(n0 + 2) * LDST + k] = f2bf(w.z);
        Wt1[(n0 + 3) * LDST + k] = f2bf(w.w);
        float4 u = *(const float4*)(W2 + (size_t)k * D + n0);
        Wt2[(n0 + 0) * LDST + k] = f2bf(u.x);
        Wt2[(n0 + 1) * LDST + k] = f2bf(u.y);
        Wt2[(n0 + 2) * LDST + k] = f2bf(u.z);
        Wt2[(n0 + 3) * LDST + k] = f2bf(u.w);
    }
    for (int c = tid; c < D; c += 256) {
        float a = gamma[c] * rsqrtf(rv[c] + BN_EPS);
        alpha_s[c] = a;
        betac_s[c] = beta[c] + (b1[c] - rm[c]) * a;  // bias folded into BN shift
        b2_s[c] = b2[c];
    }
    __syncthreads();

    const int wave = tid >> 6;        // 0..3 -> rows 16w..16w+15
    const int lane = tid & 63;
    const int lrow = lane & 15;       // m (or n) within a 16-tile
    const int lquad = lane >> 4;      // 0..3 -> k-group, and C rows lquad*4..+3

    const int ntiles = (N_NODES + MLP_ROWS - 1) / MLP_ROWS;   // 782
    for (int g = blockIdx.x; g < ntiles; g += gridDim.x) {
        const int row0 = g * MLP_ROWS;
        // ---- stage A tile (fp32 global -> bf16 LDS, zero-fill OOB rows) ----
        for (int i = tid; i < MLP_ROWS * (D / 4); i += 256) {
            const int r = i >> 5;
            const int c0 = (i & 31) * 4;
            const int rr = row0 + r;
            float4 v = make_float4(0.f, 0.f, 0.f, 0.f);
            if (rr < N_NODES) v = *(const float4*)(io + (size_t)rr * D + c0);
            union { unsigned short s[4]; unsigned long long u; } p;
            p.s[0] = f2bf(v.x); p.s[1] = f2bf(v.y); p.s[2] = f2bf(v.z); p.s[3] = f2bf(v.w);
            *(unsigned long long*)&At[r * LDST + c0] = p.u;
        }
        __syncthreads();

        // ---- GEMM1: C1 = A @ W1  (A-frag m=lane&15, k=quad*8+j; B-frag n=lane&15) ----
        floatx4 acc[8];
#pragma unroll
        for (int ct = 0; ct < 8; ct++) acc[ct] = (floatx4){0.f, 0.f, 0.f, 0.f};
#pragma unroll
        for (int ks = 0; ks < 4; ks++) {
            short8 a = *(const short8*)&At[(wave * 16 + lrow) * LDST + ks * 32 + lquad * 8];
#pragma unroll
            for (int ct = 0; ct < 8; ct++) {
                short8 b = *(const short8*)&Wt1[(ct * 16 + lrow) * LDST + ks * 32 + lquad * 8];
                acc[ct] = __builtin_amdgcn_mfma_f32_16x16x32_bf16(a, b, acc[ct], 0, 0, 0);
            }
        }
        // ---- epilogue 1: BN+ReLU, write T1 (bf16) back into At in A-layout ----
        // C layout: col = lane&15, row = lquad*4 + reg  (verified m89)
#pragma unroll
        for (int ct = 0; ct < 8; ct++) {
            const int c = ct * 16 + lrow;
            const float al = alpha_s[c], bt = betac_s[c];
#pragma unroll
            for (int j = 0; j < 4; j++) {
                const int r = wave * 16 + lquad * 4 + j;
                float v = acc[ct][j] * al + bt;
                v = v > 0.f ? v : 0.f;
                At[r * LDST + c] = f2bf(v);
            }
        }
        __syncthreads();

        // ---- GEMM2: C2 = T1 @ W2 ----
        floatx4 acc2[8];
#pragma unroll
        for (int ct = 0; ct < 8; ct++) acc2[ct] = (floatx4){0.f, 0.f, 0.f, 0.f};
#pragma unroll
        for (int ks = 0; ks < 4; ks++) {
            short8 a = *(const short8*)&At[(wave * 16 + lrow) * LDST + ks * 32 + lquad * 8];
#pragma unroll
            for (int ct = 0; ct < 8; ct++) {
                short8 b = *(const short8*)&Wt2[(ct * 16 + lrow) * LDST + ks * 32 + lquad * 8];
                acc2[ct] = __builtin_amdgcn_mfma_f32_16x16x32_bf16(a, b, acc2[ct], 0, 0, 0);
            }
        }
        // ---- epilogue 2: +b2, optional ReLU, store fp32 ----
#pragma unroll
        for (int ct = 0; ct < 8; ct++) {
            const int c = ct * 16 + lrow;
            const float bb = b2_s[c];
#pragma unroll
            for (int j = 0; j < 4; j++) {
                const int r = row0 + wave * 16 + lquad * 4 + j;
                if (r < N_NODES) {
                    float v = acc2[ct][j] + bb;
                    if (relu2) v = v > 0.f ? v : 0.f;
                    io[(size_t)r * D + c] = v;
                }
            }
        }
        __syncthreads();   // protect At before next tile's staging
    }
}

// ---------------- global mean pool (batch is sorted) ----------------
__global__ __launch_bounds__(128) void pool_kernel(
    const float* __restrict__ xin, const int* __restrict__ batch,
    float* __restrict__ out)
{
    const int g = blockIdx.x;
    const int t = threadIdx.x;
    int lo = 0, hi = N_NODES;
    while (lo < hi) { int m = (lo + hi) >> 1; if (batch[m] < g) lo = m + 1; else hi = m; }
    int lo2 = lo, hi2 = N_NODES;
    while (lo2 < hi2) { int m = (lo2 + hi2) >> 1; if (batch[m] < g + 1) lo2 = m + 1; else hi2 = m; }
    float sum = 0.f;
    for (int rr = lo; rr < lo2; rr++) sum += xin[(size_t)rr * D + t];
    const int cnt = lo2 - lo;
    out[g * D + t] = sum / (float)(cnt > 0 ? cnt : 1);
}

extern "C" void kernel_launch(void* const* d_in, const int* in_sizes, int n_in,
                              void* d_out, int out_size, void* d_ws, size_t ws_size,
                              hipStream_t stream) {
    const float* x     = (const float*)d_in[0];
    const int*   ei    = (const int*)  d_in[1];
    const float* ea    = (const float*)d_in[2];
    const int*   batch = (const int*)  d_in[3];
    const float* We    = (const float*)d_in[4];
    const float* be    = (const float*)d_in[5];
    const float* W1    = (const float*)d_in[6];
    const float* b1    = (const float*)d_in[7];
    const float* gamma = (const float*)d_in[8];
    const float* beta  = (const float*)d_in[9];
    const float* rm    = (const float*)d_in[10];
    const float* rv    = (const float*)d_in[11];
    const float* W2    = (const float*)d_in[12];
    const float* b2    = (const float*)d_in[13];
    float* out = (float*)d_out;

    float* bufA = (float*)d_ws;
    float* bufB = bufA + (size_t)N_NODES * D;

    const float* cur = x;
    float* agg = bufA;
    float* other = bufB;
    for (int i = 0; i < N_LAYERS; i++) {
        copy_f4<<<1024, 256, 0, stream>>>((const float4*)cur, (float4*)agg, N_NODES * D / 4);
        edge_kernel<<<4096, 128, 0, stream>>>(cur, ei, ea, We + (size_t)i * DE * D, be + (size_t)i * D, agg);
        mlp_kernel<<<256, 256, 0, stream>>>(agg,
                                            W1 + (size_t)i * D * D, b1 + (size_t)i * D,
                                            gamma + (size_t)i * D, beta + (size_t)i * D,
                                            rm + (size_t)i * D, rv + (size_t)i * D,
                                            W2 + (size_t)i * D * D, b2 + (size_t)i * D,
                                            (i != N_LAYERS - 1) ? 1 : 0);
        cur = agg;
        float* t = agg; agg = other; other = t;
    }
    pool_kernel<<<N_GRAPHS, D, 0, stream>>>(cur, batch, out);
}